// Round 6
// baseline (355.939 us; speedup 1.0000x reference)
//
#include <hip/hip_runtime.h>

typedef __bf16 bf16x8 __attribute__((ext_vector_type(8)));
typedef float f32x16 __attribute__((ext_vector_type(16)));
typedef unsigned short us8 __attribute__((ext_vector_type(8)));

#define AS1 __attribute__((address_space(1)))
#define AS3 __attribute__((address_space(3)))

__device__ __forceinline__ unsigned short f2bf(float x) {
  unsigned int u = __float_as_uint(x);
  u += 0x7fffu + ((u >> 16) & 1u);   // RNE
  return (unsigned short)(u >> 16);
}
__device__ __forceinline__ float bf2f(unsigned short u) {
  return __uint_as_float(((unsigned int)u) << 16);
}
__device__ __forceinline__ void async_copy16(const void* g, void* l) {
  __builtin_amdgcn_global_load_lds((AS1 void*)(g), (AS3 void*)(l), 16, 0, 0);
}

// raw barrier (no compiler-inserted full waitcnt drain) + counted vmem waits.
#define BARRIER() asm volatile("s_barrier" ::: "memory")
#define WAITV(n) asm volatile("s_waitcnt vmcnt(" #n ")" ::: "memory")

// ------------- prep: all f32->bf16 conversions + P zeroing, one launch -------------
__global__ void __launch_bounds__(256) k_prep(const float* __restrict__ x,
                                              const float* __restrict__ W1,
                                              const float* __restrict__ W2,
                                              const float* __restrict__ W3,
                                              unsigned short* __restrict__ Xb,
                                              unsigned short* __restrict__ W1b,
                                              unsigned short* __restrict__ W2b,
                                              unsigned short* __restrict__ W3b,
                                              float* __restrict__ P) {
  const long n1 = 2097152, n2 = 524288, n3 = 1048576, n4 = 524288;
  long i = (long)blockIdx.x * 256 + threadIdx.x;   // float4 group index
  const float* s = nullptr;
  unsigned short* d = nullptr;
  long j = i;
  if (i < n1)                { s = x;  d = Xb; }
  else if ((j -= n1) < n2)   { s = W1; d = W1b; }
  else if ((j -= n2) < n3)   { s = W2; d = W2b; }
  else if ((j -= n3) < n4) {
    // W3: [1000,2048] -> padded [1024,2048], zero rows >= 1000
    ushort4 o;
    if ((j >> 9) < 1000) {
      float4 v = ((const float4*)W3)[j];
      o.x = f2bf(v.x); o.y = f2bf(v.y); o.z = f2bf(v.z); o.w = f2bf(v.w);
    } else { o.x = 0; o.y = 0; o.z = 0; o.w = 0; }
    ((ushort4*)W3b)[j] = o;
    return;
  } else {
    j -= n4;                                        // 0..2047 -> zero P (2 buffers)
    ((float4*)P)[j] = (float4){0.f, 0.f, 0.f, 0.f};
    return;
  }
  float4 v = ((const float4*)s)[j];
  ushort4 o;
  o.x = f2bf(v.x); o.y = f2bf(v.y); o.z = f2bf(v.z); o.w = f2bf(v.w);
  ((ushort4*)d)[j] = o;
}

// ---------------- GEMM: C[M,N] = A[M,K] * B[N,K]^T, bf16 in -----------------------
// r13: BM=128, BN=256, BK=32, 4 waves (2Mx2N, wave tile 64x128), 32x32x16 MFMA,
// double-buffered 48 KiB LDS -> **2 independent blocks/CU** (the m97/m114 overlap
// mechanism: the other resident block fills this block's WAITV+barrier stalls).
// r5-r12 lesson: at 128KiB LDS only 1 block/CU fits and no intra-block schedule
// (phased r8=71.5us, fence-free r12=85us) overlaps pipes. Grid 512 blocks (L2).
// K-loop = r12's proven-correct fence-free tile: {WAITV(0); BARRIER; stage(t+1);
// 2 unfenced ks-steps of (2 A + 4 B ds_read_b128) + 8 MFMA}. Per-FLOP LDS traffic
// identical to r8. Rows are 64B ([row][32] bf16): staging issue = 1KB = 16 rows;
// LDS slot s of row r holds global chunk s^(r&3) (lane: chunk (lane&3)^((lane>>2)&3));
// read slot = (2ks+khi)^(l31&3) -> each 4-bank group gets exactly 4 dwords per
// 32-lane round (balanced). No setprio (m190: no phase-split -> neutral/harmful).
template <bool OUTBF16, bool STATS>
__global__ void __launch_bounds__(256, 2) k_gemm(const unsigned short* __restrict__ A,
                                                 const unsigned short* __restrict__ B,
                                                 void* __restrict__ Cout,
                                                 void* __restrict__ Cout2, int K,
                                                 int lda, int ldb, int ldc,
                                                 float* __restrict__ P) {
  __shared__ __align__(16) unsigned short lA[2][128 * 32];   // 8 KB each
  __shared__ __align__(16) unsigned short lB[2][256 * 32];   // 16 KB each
  const int tid = threadIdx.x;
  const int wave = tid >> 6;                      // 0..3
  const int lane = tid & 63;
  const int l31 = lane & 31;
  const int khi = lane >> 5;                      // 0..1
  const int s3 = l31 & 3;                         // read-swizzle key (row&3)
  const int wrh = wave >> 1;                      // 0..1 -> row offset *64
  const int wcn = wave & 1;                       // 0..1 -> col offset *128

  // XCD-aware bijective remap (f&7 = XCD; each XCD owns a contiguous m-stripe)
  const int f = blockIdx.x + gridDim.x * blockIdx.y;
  const int xcd = f & 7;
  const int fi = f >> 3;
  const int nblk = fi % gridDim.x;
  const int mblk = fi / gridDim.x + (gridDim.y >> 3) * xcd;
  const long m0 = (long)mblk * 128;
  const long n0 = (long)nblk * 256;
  const long koff = (long)blockIdx.z * K;
  const int NT = K >> 5;

  // staging: one issue = 64 lanes x 16B = 16 rows x 64B. lane -> row lane>>2,
  // chunk (lane&3)^((lane>>2)&3) so LDS slot s of row r holds chunk s^(r&3).
  const int rsub = lane >> 2;                     // 0..15
  const int qg = ((lane & 3) ^ (rsub & 3)) * 8;
  const unsigned short* gAw = A + (m0 + 32 * wave + rsub) * (long)lda + koff + qg;
  const unsigned short* gBw = B + (n0 + 64 * wave + rsub) * (long)ldb + koff + qg;
  const long lda16 = (long)lda * 16;
  const long ldb16 = (long)ldb * 16;

  f32x16 acc[2][4];
#pragma unroll
  for (int i = 0; i < 2; ++i)
#pragma unroll
    for (int j = 0; j < 4; ++j) acc[i][j] = (f32x16)(0.f);

  auto stage = [&](int buf, long kk) {
    unsigned short* dA = &lA[buf][0] + wave * 1024;   // 2 issues x 512 ushorts
    unsigned short* dB = &lB[buf][0] + wave * 2048;   // 4 issues x 512 ushorts
#pragma unroll
    for (int i = 0; i < 2; ++i)
      async_copy16(gAw + (long)i * lda16 + kk, dA + i * 512);
#pragma unroll
    for (int j = 0; j < 4; ++j)
      async_copy16(gBw + (long)j * ldb16 + kk, dB + j * 512);
  };

  stage(0, 0);
  for (int t = 0; t < NT; ++t) {
    const unsigned short* lAc = &lA[t & 1][0];
    const unsigned short* lBc = &lB[t & 1][0];
    WAITV(0);          // waits this wave's buf[t] stages, issued one full tile ago
    BARRIER();         // all waves' stages landed -> buf[t] valid block-wide
    if (t + 1 < NT) stage((t + 1) & 1, (long)(t + 1) * 32);
#pragma unroll
    for (int ks = 0; ks < 2; ++ks) {             // K-step of 16, unfenced
      const int off = ((ks * 2 + khi) ^ s3) * 8;
      bf16x8 af[2], bfr[4];
#pragma unroll
      for (int m = 0; m < 2; ++m)
        af[m] = *(const bf16x8*)&lAc[(wrh * 64 + m * 32 + l31) * 32 + off];
#pragma unroll
      for (int n = 0; n < 4; ++n)
        bfr[n] = *(const bf16x8*)&lBc[(wcn * 128 + n * 32 + l31) * 32 + off];
#pragma unroll
      for (int m = 0; m < 2; ++m)
#pragma unroll
        for (int n = 0; n < 4; ++n)
          acc[m][n] = __builtin_amdgcn_mfma_f32_32x32x16_bf16(af[m], bfr[n], acc[m][n], 0, 0, 0);
    }
  }

  // C/D layout: col = lane&31, row = (reg&3) + 8*(reg>>2) + 4*(lane>>5)
  const int rbase = 4 * khi;
  const long crow0 = m0 + wrh * 64;
  const long ccol0 = n0 + wcn * 128;
  if (OUTBF16) {
    unsigned short* C = (unsigned short*)(blockIdx.z ? Cout2 : Cout);
#pragma unroll
    for (int m = 0; m < 2; ++m)
#pragma unroll
      for (int n = 0; n < 4; ++n) {
        long col = ccol0 + n * 32 + l31;
#pragma unroll
        for (int reg = 0; reg < 16; ++reg) {
          long row = crow0 + m * 32 + (reg & 3) + 8 * (reg >> 2) + rbase;
          C[row * (long)ldc + col] = f2bf(acc[m][n][reg]);
        }
      }
  } else {
    float* C = (float*)(blockIdx.z ? Cout2 : Cout);
#pragma unroll
    for (int m = 0; m < 2; ++m)
#pragma unroll
      for (int n = 0; n < 4; ++n) {
        long col = ccol0 + n * 32 + l31;
#pragma unroll
        for (int reg = 0; reg < 16; ++reg) {
          long row = crow0 + m * 32 + (reg & 3) + 8 * (reg >> 2) + rbase;
          C[row * (long)ldc + col] = acc[m][n][reg];
        }
      }
  }

  if (STATS) {
    // per-column sum/sumsq over the block's 128 rows -> P[n0..+255], P[2048+n0..]
    float* sred = (float*)&lA[0][0];   // 512 floats (2KB of the 8KB buffer)
    __syncthreads();
    sred[tid] = 0.f;                   // sum[0..255]
    sred[256 + tid] = 0.f;             // sumsq[0..255]
    __syncthreads();
#pragma unroll
    for (int n = 0; n < 4; ++n) {
      float s = 0.f, s2 = 0.f;
#pragma unroll
      for (int m = 0; m < 2; ++m)
#pragma unroll
        for (int reg = 0; reg < 16; ++reg) {
          float v = acc[m][n][reg];
          s += v;
          s2 = fmaf(v, v, s2);
        }
      int cl = wcn * 128 + n * 32 + l31;      // 0..255
      atomicAdd(&sred[cl], s);
      atomicAdd(&sred[256 + cl], s2);
    }
    __syncthreads();
    atomicAdd(&P[n0 + tid], sred[tid]);
    atomicAdd(&P[2048 + n0 + tid], sred[256 + tid]);
  }
}

// ------- fused BN-finalize + BN-apply + relu + row-norm + hyperbolic factor -------
// One wave per row. Each lane handles cols (lane+64c)*8..+7, c=0..3; scale/shift
// computed per-lane from P/g/be (L2-hit redundant reads).
template <bool STAGE2>
__global__ void __launch_bounds__(256) k_fuse(const unsigned short* __restrict__ Zb,
                                              const float* __restrict__ P,
                                              const float* __restrict__ g,
                                              const float* __restrict__ be,
                                              unsigned short* __restrict__ Ab) {
  const int t = threadIdx.x, wave = t >> 6, lane = t & 63;
  const long row = (long)blockIdx.x * 4 + wave;

  float sc[32], sh[32];
#pragma unroll
  for (int c = 0; c < 4; ++c) {
    int b4 = (lane + 64 * c) * 2;                 // float4 index of col base
    float4 s0 = ((const float4*)P)[b4],       s1 = ((const float4*)P)[b4 + 1];
    float4 q0 = ((const float4*)P)[512 + b4], q1 = ((const float4*)P)[512 + b4 + 1];
    float4 g0 = ((const float4*)g)[b4],       g1 = ((const float4*)g)[b4 + 1];
    float4 e0 = ((const float4*)be)[b4],      e1 = ((const float4*)be)[b4 + 1];
    float sm[8] = {s0.x, s0.y, s0.z, s0.w, s1.x, s1.y, s1.z, s1.w};
    float sq[8] = {q0.x, q0.y, q0.z, q0.w, q1.x, q1.y, q1.z, q1.w};
    float gg[8] = {g0.x, g0.y, g0.z, g0.w, g1.x, g1.y, g1.z, g1.w};
    float bb[8] = {e0.x, e0.y, e0.z, e0.w, e1.x, e1.y, e1.z, e1.w};
#pragma unroll
    for (int j = 0; j < 8; ++j) {
      float mean = sm[j] * (1.f / 8192.f);
      float var = sq[j] * (1.f / 8192.f) - mean * mean;
      float a = gg[j] * rsqrtf(var + 1e-5f);
      sc[c * 8 + j] = a;
      sh[c * 8 + j] = bb[j] - mean * a;
    }
  }

  const us8* zr = (const us8*)(Zb + row * 2048);
  float v[32];
  float ss = 0.f;
#pragma unroll
  for (int c = 0; c < 4; ++c) {
    us8 z8 = zr[lane + 64 * c];
#pragma unroll
    for (int j = 0; j < 8; ++j) {
      float xv = fmaxf(fmaf(bf2f(z8[j]), sc[c * 8 + j], sh[c * 8 + j]), 0.f);
      v[c * 8 + j] = xv;
      ss = fmaf(xv, xv, ss);
    }
  }
#pragma unroll
  for (int o = 32; o > 0; o >>= 1) ss += __shfl_xor(ss, o, 64);
  float n2 = ss;

  const float rsc = 0.31622776601683794f;  // sqrt(0.1)
  float fac;
  if (STAGE2) {
    float nn = sqrtf(n2);
    float vn = fmaxf(nn, 1e-8f);
    float tt = rsc * vn;
    float scl = tanhf(tt) / tt;
    float hn = scl * nn;
    float cn = fminf(fmaxf(hn, 1e-8f), 1.0f);
    float z = rsc * cn;
    fac = scl * (atanhf(z) / z);
  } else {
    fac = 0.f;
    if (n2 > 0.f) {
      float n = sqrtf(n2);
      float th = tanhf(rsc * n);
      float s = 0.9f * th / (rsc * n);
      float dn = fmaxf(s * n, 1e-8f);
      float z = rsc * dn;
      fac = -(atanhf(z) / z) * s;
    }
  }
  us8* dr = (us8*)(Ab + row * 2048);
#pragma unroll
  for (int c = 0; c < 4; ++c) {
    us8 o8;
#pragma unroll
    for (int j = 0; j < 8; ++j) o8[j] = f2bf(v[c * 8 + j] * fac);
    dr[lane + 64 * c] = o8;
  }
}

// ---- log_softmax over 1000 cols; one wave per row; sums bf16 split-K partials ----
__global__ void __launch_bounds__(256) k_lsm(const unsigned short* __restrict__ Za,
                                             const unsigned short* __restrict__ Zb2,
                                             const float* __restrict__ b3,
                                             float* __restrict__ out) {
  const int t = threadIdx.x, wave = t >> 6, lane = t & 63;
  const long row = (long)blockIdx.x * 4 + wave;
  const unsigned short* za = Za + row * 1024;
  const unsigned short* zb = Zb2 + row * 1024;
  float v[16];
  float mx = -3.4e38f;
#pragma unroll
  for (int c = 0; c < 16; ++c) {
    int col = lane + 64 * c;
    if (col < 1000) {
      v[c] = bf2f(za[col]) + bf2f(zb[col]) + b3[col];
      mx = fmaxf(mx, v[c]);
    } else v[c] = -3.4e38f;
  }
#pragma unroll
  for (int o = 32; o > 0; o >>= 1) mx = fmaxf(mx, __shfl_xor(mx, o, 64));

  float se = 0.f;
#pragma unroll
  for (int c = 0; c < 16; ++c) {
    int col = lane + 64 * c;
    if (col < 1000) se += expf(v[c] - mx);
  }
#pragma unroll
  for (int o = 32; o > 0; o >>= 1) se += __shfl_xor(se, o, 64);
  float ls = logf(se);

  float* orow = out + row * 1000;
#pragma unroll
  for (int c = 0; c < 16; ++c) {
    int col = lane + 64 * c;
    if (col < 1000) orow[col] = v[c] - mx - ls;
  }
}

extern "C" void kernel_launch(void* const* d_in, const int* in_sizes, int n_in,
                              void* d_out, int out_size, void* d_ws, size_t ws_size,
                              hipStream_t stream) {
  (void)in_sizes; (void)n_in; (void)out_size; (void)ws_size;
  const float* x   = (const float*)d_in[0];
  const float* W1  = (const float*)d_in[1];
  // d_in[2] = b1: exactly cancelled by BN (mean absorbs it)
  const float* g1  = (const float*)d_in[3];
  const float* be1 = (const float*)d_in[4];
  const float* W2  = (const float*)d_in[5];
  // d_in[6] = b2: cancelled by BN
  const float* g2  = (const float*)d_in[7];
  const float* be2 = (const float*)d_in[8];
  const float* W3  = (const float*)d_in[9];
  const float* b3  = (const float*)d_in[10];
  float* out = (float*)d_out;

  char* ws = (char*)d_ws;
  size_t off = 0;
  auto alloc = [&](size_t bytes) {
    void* p = ws + off;
    off += (bytes + 255) & ~(size_t)255;
    return p;
  };
  unsigned short* Xb  = (unsigned short*)alloc((size_t)8192 * 1024 * 2);
  unsigned short* W1b = (unsigned short*)alloc((size_t)2048 * 1024 * 2);
  unsigned short* W2b = (unsigned short*)alloc((size_t)2048 * 2048 * 2);
  unsigned short* W3b = (unsigned short*)alloc((size_t)1024 * 2048 * 2);
  unsigned short* Zb  = (unsigned short*)alloc((size_t)8192 * 2048 * 2);
  unsigned short* Ab  = (unsigned short*)alloc((size_t)8192 * 2048 * 2);
  unsigned short* Z3a = (unsigned short*)alloc((size_t)8192 * 1024 * 2);
  float* P            = (float*)alloc((size_t)2 * 4096 * 4);   // P1 | P2, zeroed by k_prep
  float* P2 = P + 4096;
  // split-K slice-1 output aliases Zb (dead after k_fuse<true>; 32 MiB >= 16 MiB)
  unsigned short* Z3b = Zb;

  // conversions + P zeroing
  k_prep<<<16392, 256, 0, stream>>>(x, W1, W2, W3, Xb, W1b, W2b, W3b, P);

  // layer 1: GEMM (+BN stats) -> fused BN-finalize+hyperbolic
  k_gemm<true, true><<<dim3(8, 64, 1), 256, 0, stream>>>(Xb, W1b, Zb, Zb, 1024, 1024, 1024, 2048, P);
  k_fuse<false><<<2048, 256, 0, stream>>>(Zb, P, g1, be1, Ab);

  // layer 2
  k_gemm<true, true><<<dim3(8, 64, 1), 256, 0, stream>>>(Ab, W2b, Zb, Zb, 2048, 2048, 2048, 2048, P2);
  k_fuse<true><<<2048, 256, 0, stream>>>(Zb, P2, g2, be2, Ab);

  // layer 3: split-K=2 in ONE launch (blockIdx.z), bf16 partials summed in k_lsm
  k_gemm<true, false><<<dim3(4, 64, 2), 256, 0, stream>>>(Ab, W3b, Z3a, Z3b, 1024, 2048, 2048, 1024, nullptr);
  k_lsm<<<2048, 256, 0, stream>>>(Z3a, Z3b, b3, out);
}

// Round 7
// 298.272 us; speedup vs baseline: 1.1933x; 1.1933x over previous
//
#include <hip/hip_runtime.h>

typedef __bf16 bf16x8 __attribute__((ext_vector_type(8)));
typedef float f32x16 __attribute__((ext_vector_type(16)));
typedef unsigned short us8 __attribute__((ext_vector_type(8)));

#define AS1 __attribute__((address_space(1)))
#define AS3 __attribute__((address_space(3)))

__device__ __forceinline__ unsigned short f2bf(float x) {
  unsigned int u = __float_as_uint(x);
  u += 0x7fffu + ((u >> 16) & 1u);   // RNE
  return (unsigned short)(u >> 16);
}
__device__ __forceinline__ float bf2f(unsigned short u) {
  return __uint_as_float(((unsigned int)u) << 16);
}
__device__ __forceinline__ void async_copy16(const void* g, void* l) {
  __builtin_amdgcn_global_load_lds((AS1 void*)(g), (AS3 void*)(l), 16, 0, 0);
}

// raw barrier (no compiler-inserted full waitcnt drain) + counted vmem waits.
#define BARRIER() asm volatile("s_barrier" ::: "memory")
#define WAITV(n) asm volatile("s_waitcnt vmcnt(" #n ")" ::: "memory")

// ------------- prep: all f32->bf16 conversions + P zeroing, one launch -------------
__global__ void __launch_bounds__(256) k_prep(const float* __restrict__ x,
                                              const float* __restrict__ W1,
                                              const float* __restrict__ W2,
                                              const float* __restrict__ W3,
                                              unsigned short* __restrict__ Xb,
                                              unsigned short* __restrict__ W1b,
                                              unsigned short* __restrict__ W2b,
                                              unsigned short* __restrict__ W3b,
                                              float* __restrict__ P) {
  const long n1 = 2097152, n2 = 524288, n3 = 1048576, n4 = 524288;
  long i = (long)blockIdx.x * 256 + threadIdx.x;   // float4 group index
  const float* s = nullptr;
  unsigned short* d = nullptr;
  long j = i;
  if (i < n1)                { s = x;  d = Xb; }
  else if ((j -= n1) < n2)   { s = W1; d = W1b; }
  else if ((j -= n2) < n3)   { s = W2; d = W2b; }
  else if ((j -= n3) < n4) {
    // W3: [1000,2048] -> padded [1024,2048], zero rows >= 1000
    ushort4 o;
    if ((j >> 9) < 1000) {
      float4 v = ((const float4*)W3)[j];
      o.x = f2bf(v.x); o.y = f2bf(v.y); o.z = f2bf(v.z); o.w = f2bf(v.w);
    } else { o.x = 0; o.y = 0; o.z = 0; o.w = 0; }
    ((ushort4*)W3b)[j] = o;
    return;
  } else {
    j -= n4;                                        // 0..2047 -> zero P (2 buffers)
    ((float4*)P)[j] = (float4){0.f, 0.f, 0.f, 0.f};
    return;
  }
  float4 v = ((const float4*)s)[j];
  ushort4 o;
  o.x = f2bf(v.x); o.y = f2bf(v.y); o.z = f2bf(v.z); o.w = f2bf(v.w);
  ((ushort4*)d)[j] = o;
}

// ---------------- GEMM: C[M,N] = A[M,K] * B[N,K]^T, bf16 in -----------------------
// r14 == r8 VERBATIM (best measured: 71.5 us @ 8192x2048x2048; r9-r13 structural
// variants all regressed 3-31us). 256x256 tile, BK=64, 8 waves (2Mx4N, wave tile
// 128x64), double-buffered 128 KiB LDS, 4-phase-per-K-tile with counted vmcnt:
// ph0:{A-q0,A-q2} ph1:{B0,B1} ph2:{B2,B3} ph3:{A-q1,A-q3}; WAITV(2) at end-ph0
// (lands this tile's late A) and end-ph3 (lands next tile's early-6). vmcnt never
// drains to 0 in the main loop; peeled last tile. Known profile: MfmaUtil 37-39%,
// SQ_LDS_BANK_CONFLICT 6.29M (= staging-write artifact, 4cyc/ds_read fixed).
template <bool OUTBF16, bool STATS>
__global__ void __launch_bounds__(512, 2) k_gemm(const unsigned short* __restrict__ A,
                                                 const unsigned short* __restrict__ B,
                                                 void* __restrict__ Cout,
                                                 void* __restrict__ Cout2, int K,
                                                 int lda, int ldb, int ldc,
                                                 float* __restrict__ P) {
  __shared__ __align__(16) unsigned short lA[2][256 * 64];   // 64 KB
  __shared__ __align__(16) unsigned short lB[2][256 * 64];   // 64 KB
  const int tid = threadIdx.x;
  const int wave = tid >> 6;
  const int lane = tid & 63;
  const int l31 = lane & 31;
  const int khi = lane >> 5;                      // 0..1
  const int r7 = l31 & 7;                         // fragment row & 7 (swizzle key)
  const int wrh = wave >> 2;                      // 0..1 -> wave row offset *128
  const int wcn = wave & 3;                       // 0..3 -> wave col offset *64

  // XCD-aware bijective remap (f&7 = XCD; each XCD owns a contiguous m-stripe)
  const int f = blockIdx.x + gridDim.x * blockIdx.y;
  const int xcd = f & 7;
  const int fi = f >> 3;
  const int nblk = fi % gridDim.x;
  const int mblk = fi / gridDim.x + (gridDim.y >> 3) * xcd;
  const long m0 = (long)mblk * 256;
  const long n0 = (long)nblk * 256;
  const long koff = (long)blockIdx.z * K;
  const int NT = K >> 6;

  // staging: one global_load_lds issue = 64 lanes x 16B = 8 rows x 64 bf16.
  // lane -> (rsub = lane>>3 row-in-issue, swizzled global chunk (lane&7)^rsub).
  const int rsub = lane >> 3;
  const int qg = ((lane & 7) ^ rsub) * 8;
  const unsigned short* gAq0 = A + (m0 +       8 * wave + rsub) * (long)lda + koff + qg;
  const unsigned short* gAq1 = A + (m0 +  64 + 8 * wave + rsub) * (long)lda + koff + qg;
  const unsigned short* gAq2 = A + (m0 + 128 + 8 * wave + rsub) * (long)lda + koff + qg;
  const unsigned short* gAq3 = A + (m0 + 192 + 8 * wave + rsub) * (long)lda + koff + qg;
  const unsigned short* gB0  = B + (n0 + 32 * wave + rsub) * (long)ldb + koff + qg;
  const unsigned short* gB1  = gB0 +  8 * (long)ldb;
  const unsigned short* gB2  = gB0 + 16 * (long)ldb;
  const unsigned short* gB3  = gB0 + 24 * (long)ldb;
  const int dAq0 = (      8 * wave) * 64;
  const int dAq1 = ( 64 + 8 * wave) * 64;
  const int dAq2 = (128 + 8 * wave) * 64;
  const int dAq3 = (192 + 8 * wave) * 64;
  const int dB0  = (32 * wave) * 64;

  f32x16 acc[4][2];
#pragma unroll
  for (int i = 0; i < 4; ++i)
#pragma unroll
    for (int j = 0; j < 2; ++j) acc[i][j] = (f32x16)(0.f);

// phase helpers: all indices compile-time after unroll (no scratch).
#define PH_READS(rh, kh, DOB)                                                        \
  bf16x8 af[2][2];                                                                   \
  _Pragma("unroll") for (int i = 0; i < 2; ++i) {                                    \
    _Pragma("unroll") for (int ks = 0; ks < 2; ++ks) {                               \
      af[i][ks] = *(const bf16x8*)&lAc[(wrh * 128 + (rh) * 64 + i * 32 + l31) * 64 + \
                                       ((((kh) * 2 + ks) * 2 + khi) ^ r7) * 8];      \
    }                                                                                \
  }                                                                                  \
  if (DOB) {                                                                         \
    _Pragma("unroll") for (int j = 0; j < 2; ++j) {                                  \
      _Pragma("unroll") for (int ks = 0; ks < 2; ++ks) {                             \
        bf[j][ks] = *(const bf16x8*)&lBc[(wcn * 64 + j * 32 + l31) * 64 +            \
                                         ((((kh) * 2 + ks) * 2 + khi) ^ r7) * 8];    \
      }                                                                              \
    }                                                                                \
  }

#define PH_MFMA(rh)                                                                 \
  __builtin_amdgcn_s_setprio(1);                                                    \
  _Pragma("unroll") for (int ks = 0; ks < 2; ++ks) {                                 \
    _Pragma("unroll") for (int i = 0; i < 2; ++i) {                                  \
      _Pragma("unroll") for (int j = 0; j < 2; ++j) {                                \
        acc[(rh) * 2 + i][j] = __builtin_amdgcn_mfma_f32_32x32x16_bf16(              \
            af[i][ks], bf[j][ks], acc[(rh) * 2 + i][j], 0, 0, 0);                    \
      }                                                                              \
    }                                                                                \
  }                                                                                  \
  __builtin_amdgcn_s_setprio(0);

  // prologue: stage tile 0 (6 early, 2 late), land the early set, keep late in flight
  {
    unsigned short* lAn = &lA[0][0];
    unsigned short* lBn = &lB[0][0];
    async_copy16(gAq0, lAn + dAq0);
    async_copy16(gAq2, lAn + dAq2);
    async_copy16(gB0,  lBn + dB0);
    async_copy16(gB1,  lBn + dB0 + 8 * 64);
    async_copy16(gB2,  lBn + dB0 + 16 * 64);
    async_copy16(gB3,  lBn + dB0 + 24 * 64);
    async_copy16(gAq1, lAn + dAq1);
    async_copy16(gAq3, lAn + dAq3);
    WAITV(2);
    BARRIER();
  }

  for (int t = 0; t < NT - 1; ++t) {
    const unsigned short* lAc = &lA[t & 1][0];
    const unsigned short* lBc = &lB[t & 1][0];
    unsigned short* lAn = &lA[(t + 1) & 1][0];
    unsigned short* lBn = &lB[(t + 1) & 1][0];
    const long kk = (long)(t + 1) * 64;
    bf16x8 bf[2][2];
    { // ph0: (rh0, kh0) — needs A-q0/q2 + B (the "early" set of tile t)
      PH_READS(0, 0, 1)
      async_copy16(gAq0 + kk, lAn + dAq0);
      async_copy16(gAq2 + kk, lAn + dAq2);
      BARRIER();
      PH_MFMA(0)
      WAITV(2);        // lands A-q1/q3 of tile t (issued at t-1 ph3)
      BARRIER();
    }
    { // ph1: (rh1, kh0) — A-q1/q3 now guaranteed
      PH_READS(1, 0, 0)
      async_copy16(gB0 + kk, lBn + dB0);
      async_copy16(gB1 + kk, lBn + dB0 + 8 * 64);
      BARRIER();
      PH_MFMA(1)
      BARRIER();
    }
    { // ph2: (rh0, kh1)
      PH_READS(0, 1, 1)
      async_copy16(gB2 + kk, lBn + dB0 + 16 * 64);
      async_copy16(gB3 + kk, lBn + dB0 + 24 * 64);
      BARRIER();
      PH_MFMA(0)
      BARRIER();
    }
    { // ph3: (rh1, kh1) — issue late loads last; land t+1's early set
      PH_READS(1, 1, 0)
      async_copy16(gAq1 + kk, lAn + dAq1);
      async_copy16(gAq3 + kk, lAn + dAq3);
      BARRIER();
      PH_MFMA(1)
      WAITV(2);        // lands the 6 early loads of tile t+1; 2 late stay in flight
      BARRIER();
    }
  }

  // peeled last tile: no prefetch; one vmcnt(0) to land its late A-quarters
  {
    const unsigned short* lAc = &lA[(NT - 1) & 1][0];
    const unsigned short* lBc = &lB[(NT - 1) & 1][0];
    bf16x8 bf[2][2];
    { PH_READS(0, 0, 1) BARRIER(); PH_MFMA(0) WAITV(0); BARRIER(); }
    { PH_READS(1, 0, 0) BARRIER(); PH_MFMA(1) BARRIER(); }
    { PH_READS(0, 1, 1) BARRIER(); PH_MFMA(0) BARRIER(); }
    { PH_READS(1, 1, 0) BARRIER(); PH_MFMA(1) BARRIER(); }
  }
#undef PH_READS
#undef PH_MFMA

  // C/D layout: col = lane&31, row = (reg&3) + 8*(reg>>2) + 4*(lane>>5)
  const int rbase = 4 * khi;
  const long crow0 = m0 + wrh * 128;
  const long ccol0 = n0 + wcn * 64;
  if (OUTBF16) {
    unsigned short* C = (unsigned short*)(blockIdx.z ? Cout2 : Cout);
#pragma unroll
    for (int ig = 0; ig < 4; ++ig)
#pragma unroll
      for (int j = 0; j < 2; ++j) {
        long col = ccol0 + j * 32 + l31;
#pragma unroll
        for (int reg = 0; reg < 16; ++reg) {
          long row = crow0 + ig * 32 + (reg & 3) + 8 * (reg >> 2) + rbase;
          C[row * (long)ldc + col] = f2bf(acc[ig][j][reg]);
        }
      }
  } else {
    float* C = (float*)(blockIdx.z ? Cout2 : Cout);
#pragma unroll
    for (int ig = 0; ig < 4; ++ig)
#pragma unroll
      for (int j = 0; j < 2; ++j) {
        long col = ccol0 + j * 32 + l31;
#pragma unroll
        for (int reg = 0; reg < 16; ++reg) {
          long row = crow0 + ig * 32 + (reg & 3) + 8 * (reg >> 2) + rbase;
          C[row * (long)ldc + col] = acc[ig][j][reg];
        }
      }
  }

  if (STATS) {
    // per-column sum/sumsq over the block's 256 rows -> P[n0..+255], P[2048+n0..]
    float* sred = (float*)&lA[0][0];   // 512 floats; last tile read lA[1] (NT even)
    sred[tid] = 0.f;                   // sum[0..255] | sumsq[256..511]
    __syncthreads();
#pragma unroll
    for (int j = 0; j < 2; ++j) {
      float s = 0.f, s2 = 0.f;
#pragma unroll
      for (int ig = 0; ig < 4; ++ig)
#pragma unroll
        for (int reg = 0; reg < 16; ++reg) {
          float v = acc[ig][j][reg];
          s += v;
          s2 = fmaf(v, v, s2);
        }
      int cl = wcn * 64 + j * 32 + l31;      // 0..255
      atomicAdd(&sred[cl], s);
      atomicAdd(&sred[256 + cl], s2);
    }
    __syncthreads();
    if (tid < 256) atomicAdd(&P[n0 + tid], sred[tid]);
    else           atomicAdd(&P[2048 + n0 + tid - 256], sred[tid]);
  }
}

// ---- BN finalize: per-column scale/shift computed ONCE (was redone per-row in
// k_fuse: 8192x redundant rsqrtf + 128 L2 loads/thread). Overwrites P in place:
// P[c] = a = g*rsqrt(var+eps), P[2048+c] = be - mean*a. Same op order -> bit-identical.
__global__ void __launch_bounds__(256) k_bnfin(float* __restrict__ P,
                                               const float* __restrict__ g,
                                               const float* __restrict__ be) {
  const int c = blockIdx.x * 256 + threadIdx.x;    // 0..2047
  float mean = P[c] * (1.f / 8192.f);
  float var = P[2048 + c] * (1.f / 8192.f) - mean * mean;
  float a = g[c] * rsqrtf(var + 1e-5f);
  P[c] = a;
  P[2048 + c] = be[c] - mean * a;
}

// ------- fused BN-apply + relu + row-norm + hyperbolic factor (pure stream) -------
// One wave per row; lane handles cols (lane+64c)*8..+7, c=0..3. sc/sh are now
// precomputed per-column by k_bnfin (16 float4 L2 loads/thread, no rsqrt).
template <bool STAGE2>
__global__ void __launch_bounds__(256) k_fuse(const unsigned short* __restrict__ Zb,
                                              const float* __restrict__ P,
                                              unsigned short* __restrict__ Ab) {
  const int t = threadIdx.x, wave = t >> 6, lane = t & 63;
  const long row = (long)blockIdx.x * 4 + wave;

  float sc[32], sh[32];
#pragma unroll
  for (int c = 0; c < 4; ++c) {
    int b4 = (lane + 64 * c) * 2;                 // float4 index of col base
    float4 a0 = ((const float4*)P)[b4],       a1 = ((const float4*)P)[b4 + 1];
    float4 h0 = ((const float4*)P)[512 + b4], h1 = ((const float4*)P)[512 + b4 + 1];
    sc[c * 8 + 0] = a0.x; sc[c * 8 + 1] = a0.y; sc[c * 8 + 2] = a0.z; sc[c * 8 + 3] = a0.w;
    sc[c * 8 + 4] = a1.x; sc[c * 8 + 5] = a1.y; sc[c * 8 + 6] = a1.z; sc[c * 8 + 7] = a1.w;
    sh[c * 8 + 0] = h0.x; sh[c * 8 + 1] = h0.y; sh[c * 8 + 2] = h0.z; sh[c * 8 + 3] = h0.w;
    sh[c * 8 + 4] = h1.x; sh[c * 8 + 5] = h1.y; sh[c * 8 + 6] = h1.z; sh[c * 8 + 7] = h1.w;
  }

  const us8* zr = (const us8*)(Zb + row * 2048);
  float v[32];
  float ss = 0.f;
#pragma unroll
  for (int c = 0; c < 4; ++c) {
    us8 z8 = zr[lane + 64 * c];
#pragma unroll
    for (int j = 0; j < 8; ++j) {
      float xv = fmaxf(fmaf(bf2f(z8[j]), sc[c * 8 + j], sh[c * 8 + j]), 0.f);
      v[c * 8 + j] = xv;
      ss = fmaf(xv, xv, ss);
    }
  }
#pragma unroll
  for (int o = 32; o > 0; o >>= 1) ss += __shfl_xor(ss, o, 64);
  float n2 = ss;

  const float rsc = 0.31622776601683794f;  // sqrt(0.1)
  float fac;
  if (STAGE2) {
    float nn = sqrtf(n2);
    float vn = fmaxf(nn, 1e-8f);
    float tt = rsc * vn;
    float scl = tanhf(tt) / tt;
    float hn = scl * nn;
    float cn = fminf(fmaxf(hn, 1e-8f), 1.0f);
    float z = rsc * cn;
    fac = scl * (atanhf(z) / z);
  } else {
    fac = 0.f;
    if (n2 > 0.f) {
      float n = sqrtf(n2);
      float th = tanhf(rsc * n);
      float s = 0.9f * th / (rsc * n);
      float dn = fmaxf(s * n, 1e-8f);
      float z = rsc * dn;
      fac = -(atanhf(z) / z) * s;
    }
  }
  us8* dr = (us8*)(Ab + row * 2048);
#pragma unroll
  for (int c = 0; c < 4; ++c) {
    us8 o8;
#pragma unroll
    for (int j = 0; j < 8; ++j) o8[j] = f2bf(v[c * 8 + j] * fac);
    dr[lane + 64 * c] = o8;
  }
}

// ---- log_softmax over 1000 cols; one wave per row; vectorized us8/float4 path ----
// lane owns 8 consecutive cols per chunk: chunk0 = lane*8 (0..511, all lanes full),
// chunk1 = 512+lane*8 (512..999: lanes 0..60 full, 61..63 empty) -> no partial
// vectors at all. Za/Zb2 cols 1000..1023 are never read (padded W3 rows).
__global__ void __launch_bounds__(256) k_lsm(const unsigned short* __restrict__ Za,
                                             const unsigned short* __restrict__ Zb2,
                                             const float* __restrict__ b3,
                                             float* __restrict__ out) {
  const int t = threadIdx.x, wave = t >> 6, lane = t & 63;
  const long row = (long)blockIdx.x * 4 + wave;
  const us8* za8 = (const us8*)(Za + row * 1024);
  const us8* zb8 = (const us8*)(Zb2 + row * 1024);

  float v[16];
  float mx = -3.4e38f;
#pragma unroll
  for (int c = 0; c < 2; ++c) {
    const bool ok = (c == 0) | (lane < 61);
    if (ok) {
      us8 a8 = za8[c * 64 + lane];
      us8 b8 = zb8[c * 64 + lane];
      const float* bp = b3 + c * 512 + lane * 8;
      float4 bA = *(const float4*)bp;
      float4 bB = *(const float4*)(bp + 4);
      float bb[8] = {bA.x, bA.y, bA.z, bA.w, bB.x, bB.y, bB.z, bB.w};
#pragma unroll
      for (int j = 0; j < 8; ++j) {
        float x = bf2f(a8[j]) + bf2f(b8[j]) + bb[j];
        v[c * 8 + j] = x;
        mx = fmaxf(mx, x);
      }
    } else {
#pragma unroll
      for (int j = 0; j < 8; ++j) v[c * 8 + j] = -3.4e38f;
    }
  }
#pragma unroll
  for (int o = 32; o > 0; o >>= 1) mx = fmaxf(mx, __shfl_xor(mx, o, 64));

  float se = 0.f;
#pragma unroll
  for (int c = 0; c < 2; ++c)
#pragma unroll
    for (int j = 0; j < 8; ++j)
      if ((c == 0) | (lane < 61)) se += expf(v[c * 8 + j] - mx);
#pragma unroll
  for (int o = 32; o > 0; o >>= 1) se += __shfl_xor(se, o, 64);
  float mls = mx + logf(se);

  float* orow = out + row * 1000;
#pragma unroll
  for (int c = 0; c < 2; ++c) {
    if ((c == 0) | (lane < 61)) {
      float4 o0 = {v[c * 8 + 0] - mls, v[c * 8 + 1] - mls, v[c * 8 + 2] - mls, v[c * 8 + 3] - mls};
      float4 o1 = {v[c * 8 + 4] - mls, v[c * 8 + 5] - mls, v[c * 8 + 6] - mls, v[c * 8 + 7] - mls};
      float* op = orow + c * 512 + lane * 8;
      *(float4*)op = o0;
      *(float4*)(op + 4) = o1;
    }
  }
}

extern "C" void kernel_launch(void* const* d_in, const int* in_sizes, int n_in,
                              void* d_out, int out_size, void* d_ws, size_t ws_size,
                              hipStream_t stream) {
  (void)in_sizes; (void)n_in; (void)out_size; (void)ws_size;
  const float* x   = (const float*)d_in[0];
  const float* W1  = (const float*)d_in[1];
  // d_in[2] = b1: exactly cancelled by BN (mean absorbs it)
  const float* g1  = (const float*)d_in[3];
  const float* be1 = (const float*)d_in[4];
  const float* W2  = (const float*)d_in[5];
  // d_in[6] = b2: cancelled by BN
  const float* g2  = (const float*)d_in[7];
  const float* be2 = (const float*)d_in[8];
  const float* W3  = (const float*)d_in[9];
  const float* b3  = (const float*)d_in[10];
  float* out = (float*)d_out;

  char* ws = (char*)d_ws;
  size_t off = 0;
  auto alloc = [&](size_t bytes) {
    void* p = ws + off;
    off += (bytes + 255) & ~(size_t)255;
    return p;
  };
  unsigned short* Xb  = (unsigned short*)alloc((size_t)8192 * 1024 * 2);
  unsigned short* W1b = (unsigned short*)alloc((size_t)2048 * 1024 * 2);
  unsigned short* W2b = (unsigned short*)alloc((size_t)2048 * 2048 * 2);
  unsigned short* W3b = (unsigned short*)alloc((size_t)1024 * 2048 * 2);
  unsigned short* Zb  = (unsigned short*)alloc((size_t)8192 * 2048 * 2);
  unsigned short* Ab  = (unsigned short*)alloc((size_t)8192 * 2048 * 2);
  unsigned short* Z3a = (unsigned short*)alloc((size_t)8192 * 1024 * 2);
  float* P            = (float*)alloc((size_t)2 * 4096 * 4);   // P1 | P2, zeroed by k_prep
  float* P2 = P + 4096;
  // split-K slice-1 output aliases Zb (dead after k_fuse<true>; 32 MiB >= 16 MiB)
  unsigned short* Z3b = Zb;

  // conversions + P zeroing
  k_prep<<<16392, 256, 0, stream>>>(x, W1, W2, W3, Xb, W1b, W2b, W3b, P);

  // layer 1: GEMM (+BN stats) -> BN finalize -> fused BN-apply+hyperbolic
  k_gemm<true, true><<<dim3(8, 32, 1), 512, 0, stream>>>(Xb, W1b, Zb, Zb, 1024, 1024, 1024, 2048, P);
  k_bnfin<<<8, 256, 0, stream>>>(P, g1, be1);
  k_fuse<false><<<2048, 256, 0, stream>>>(Zb, P, Ab);

  // layer 2
  k_gemm<true, true><<<dim3(8, 32, 1), 512, 0, stream>>>(Ab, W2b, Zb, Zb, 2048, 2048, 2048, 2048, P2);
  k_bnfin<<<8, 256, 0, stream>>>(P2, g2, be2);
  k_fuse<true><<<2048, 256, 0, stream>>>(Zb, P2, Ab);

  // layer 3: split-K=2 in ONE launch (blockIdx.z), bf16 partials summed in k_lsm
  k_gemm<true, false><<<dim3(4, 32, 2), 512, 0, stream>>>(Ab, W3b, Z3a, Z3b, 1024, 2048, 2048, 1024, nullptr);
  k_lsm<<<2048, 256, 0, stream>>>(Z3a, Z3b, b3, out);
}